// Round 4
// baseline (123.015 us; speedup 1.0000x reference)
//
#include <hip/hip_runtime.h>

// Problem constants (B=1): inputs (N=32768, D=1024) f32, tag_to_token (T=128, N) f32,
// gat_mask (T, T) i32. Output (T, D) f32.
#define NTOK 32768
#define NTAG 128
#define DDIM 1024
#define TOKS_PER_BLK 32

// ws layout:
//   P       : 128*1024 f32 = 524288 B  (unscaled per-tag sums)
//   cnt     : 128 i32      = 512 B
//   lastTag : 32768 i32    = 131072 B

// ---------------------------------------------------------------------------
// Kernel 1: lastTag[n] = max{ j : t2t[j][n] > 0 } (or -1), fused with zeroing
// P and cnt (plain stores; atomics to these happen only in later kernels, so
// kernel ordering makes this safe). Math fact: deduce_direct_string's
// temp[i][n] is 1 iff i is the LAST covering tag of n (for ANY 0/1 coverage),
// so the row-normalized t2t is one-hot per token / cnt[tag].
// Block = 128 tokens x all 128 rows: thread (c = tid>>5, g = tid&31) scans
// row-chunk c (16 rows, unrolled -> 16 loads in flight) for token group g
// (4 tokens, float4); LDS reduce over the 8 chunks.
// ---------------------------------------------------------------------------
__global__ __launch_bounds__(256) void k_lasttag(const float* __restrict__ t2t,
                                                 int* __restrict__ lastTag,
                                                 float* __restrict__ P,
                                                 int* __restrict__ cnt) {
    __shared__ int part[8][32][4];
    const int tid = threadIdx.x;

    // zero P (131072 floats over 65536 threads -> one float2 each) and cnt
    const int gid = blockIdx.x * 256 + tid;
    reinterpret_cast<float2*>(P)[gid] = make_float2(0.f, 0.f);
    if (gid < NTAG) cnt[gid] = 0;

    const int g = tid & 31;   // token group (4 tokens)
    const int c = tid >> 5;   // row chunk (16 rows)
    const int n0 = blockIdx.x * 128 + g * 4;
    const int j0 = c * 16;
    int l0 = -1, l1 = -1, l2 = -1, l3 = -1;
#pragma unroll
    for (int jj = 0; jj < 16; ++jj) {
        const int j = j0 + jj;
        const float4 v = *reinterpret_cast<const float4*>(t2t + (size_t)j * NTOK + n0);
        if (v.x > 0.f) l0 = j;
        if (v.y > 0.f) l1 = j;
        if (v.z > 0.f) l2 = j;
        if (v.w > 0.f) l3 = j;
    }
    part[c][g][0] = l0;
    part[c][g][1] = l1;
    part[c][g][2] = l2;
    part[c][g][3] = l3;
    __syncthreads();

    if (tid < 128) {
        int m = -1;
#pragma unroll
        for (int cc = 0; cc < 8; ++cc) m = max(m, part[cc][tid >> 2][tid & 3]);
        lastTag[blockIdx.x * 128 + tid] = m;
    }
}

// ---------------------------------------------------------------------------
// Kernel 2: segmented sum, software-pipelined. Each block: 32 tokens x 1024
// cols (thread -> 4 cols, float4); grid = 1024. Tokens processed in 4 groups
// of 8 held in registers; next group prefetched while accumulating current
// (static indices only -> stays in VGPRs). On a tag change the run's partial
// sum is flushed with 4 atomicAdds into P[tag][col]; thread 0 also adds the
// run length to cnt[tag] (replaces the old histogram kernel). For the real
// nested data each block is a single run -> atomics rare and uncontended.
// ---------------------------------------------------------------------------
__global__ __launch_bounds__(256) void k_segsum(const float* __restrict__ inp,
                                                const int* __restrict__ lastTag,
                                                float* __restrict__ P,
                                                int* __restrict__ cnt) {
    __shared__ int tags[TOKS_PER_BLK];
    const int tid = threadIdx.x;
    const int n0 = blockIdx.x * TOKS_PER_BLK;
    if (tid < TOKS_PER_BLK) tags[tid] = lastTag[n0 + tid];
    __syncthreads();

    const int col = tid * 4;
    // token k's float4 for this thread: src[k * 256]
    const float4* src = reinterpret_cast<const float4*>(inp) + (size_t)n0 * 256 + tid;

    float4 va[8], vb[8];
#pragma unroll
    for (int k = 0; k < 8; ++k) va[k] = src[(size_t)k * 256];

    float4 acc = make_float4(0.f, 0.f, 0.f, 0.f);
    int cur = tags[0];
    int runlen = 0;

#pragma unroll
    for (int gr = 0; gr < 4; ++gr) {
        if (gr < 3) {
#pragma unroll
            for (int k = 0; k < 8; ++k)
                vb[k] = src[(size_t)(gr + 1) * 8 * 256 + (size_t)k * 256];
        }
#pragma unroll
        for (int k = 0; k < 8; ++k) {
            const int tg = tags[gr * 8 + k];
            if (tg != cur) {  // wave-uniform (tags uniform across lanes)
                if (cur >= 0) {
                    float* p = P + (size_t)cur * DDIM + col;
                    atomicAdd(p + 0, acc.x);
                    atomicAdd(p + 1, acc.y);
                    atomicAdd(p + 2, acc.z);
                    atomicAdd(p + 3, acc.w);
                    if (tid == 0) atomicAdd(&cnt[cur], runlen);
                }
                acc = make_float4(0.f, 0.f, 0.f, 0.f);
                cur = tg;
                runlen = 0;
            }
            if (tg >= 0) {
                acc.x += va[k].x;
                acc.y += va[k].y;
                acc.z += va[k].z;
                acc.w += va[k].w;
                ++runlen;
            }
        }
#pragma unroll
        for (int k = 0; k < 8; ++k) va[k] = vb[k];
    }
    if (cur >= 0) {
        float* p = P + (size_t)cur * DDIM + col;
        atomicAdd(p + 0, acc.x);
        atomicAdd(p + 1, acc.y);
        atomicAdd(p + 2, acc.z);
        atomicAdd(p + 3, acc.w);
        if (tid == 0) atomicAdd(&cnt[cur], runlen);
    }
}

// ---------------------------------------------------------------------------
// Kernel 3: triangular recurrence. deduce_child(gm) == gm for ANY input
// (inner loop provably a no-op: rows j>i are still zero at outer step i).
// o[i] = sum_t gm[i][t] * o_cur[t], i = 127..0 -> independent per column d.
// One thread per column; column in LDS; per-row gm as two 64-bit masks built
// with coalesced row reads + __ballot (replaces 8192 scalar loads/block).
// 1/cnt scaling fused into the column load.
// ---------------------------------------------------------------------------
__global__ __launch_bounds__(64) void k_recur(const float* __restrict__ P,
                                              const int* __restrict__ gm,
                                              const int* __restrict__ cnt,
                                              float* __restrict__ out) {
    __shared__ float o[NTAG][64];                // 32 KB
    __shared__ unsigned long long msk[NTAG][2];  // 2 KB
    __shared__ float inv[NTAG];
    const int tid = threadIdx.x;  // 0..63
    const int col = blockIdx.x * 64 + tid;

    // masks via ballot: per row, two coalesced 256B loads + two ballots
#pragma unroll 4
    for (int r = 0; r < NTAG; ++r) {
        const int a = gm[r * NTAG + tid];
        const int b = gm[r * NTAG + 64 + tid];
        const unsigned long long m0 = __ballot(a != 0);
        const unsigned long long m1 = __ballot(b != 0);
        if (tid == 0) {
            msk[r][0] = m0;
            msk[r][1] = m1;
        }
    }
    for (int r = tid; r < NTAG; r += 64) inv[r] = 1.0f / (float)cnt[r];
    __syncthreads();

#pragma unroll 8
    for (int t = 0; t < NTAG; ++t)
        o[t][tid] = P[(size_t)t * DDIM + col] * inv[t];

    for (int i = NTAG - 1; i >= 0; --i) {
        unsigned long long m0 = msk[i][0], m1 = msk[i][1];
        float a = 0.f, b = 0.f;
        while (m0) {
            const int t = __ffsll((unsigned long long)m0) - 1;
            m0 &= (m0 - 1);
            a += o[t][tid];
        }
        while (m1) {
            const int t = __ffsll((unsigned long long)m1) + 63;
            m1 &= (m1 - 1);
            b += o[t][tid];
        }
        o[i][tid] = a + b;
    }

#pragma unroll 4
    for (int i = 0; i < NTAG; ++i)
        out[(size_t)i * DDIM + col] = o[i][tid];
}

// ---------------------------------------------------------------------------
extern "C" void kernel_launch(void* const* d_in, const int* in_sizes, int n_in,
                              void* d_out, int out_size, void* d_ws, size_t ws_size,
                              hipStream_t stream) {
    const float* inp = (const float*)d_in[0];  // (N, D)
    const float* t2t = (const float*)d_in[1];  // (T, N)
    const int* gm = (const int*)d_in[2];       // (T, T)
    float* out = (float*)d_out;                // (T, D)

    char* ws = (char*)d_ws;
    float* P = (float*)ws;                     // 524288 B
    int* cnt = (int*)(ws + 524288);            // 512 B
    int* lastTag = (int*)(ws + 524288 + 512);  // 131072 B

    k_lasttag<<<NTOK / 128, 256, 0, stream>>>(t2t, lastTag, P, cnt);
    k_segsum<<<NTOK / TOKS_PER_BLK, 256, 0, stream>>>(inp, lastTag, P, cnt);
    k_recur<<<DDIM / 64, 64, 0, stream>>>(P, gm, cnt, out);
}

// Round 5
// 59.803 us; speedup vs baseline: 2.0570x; 2.0570x over previous
//
#include <hip/hip_runtime.h>

// Problem constants (B=1): inputs (N=32768, D=1024) f32, tag_to_token (T=128, N) f32,
// gat_mask (T, T) i32. Output (T, D) f32.
#define NTOK 32768
#define NTAG 128
#define DDIM 1024
#define TOKS_PER_BLK 32

// ws layout:
//   P       : 128*1024 f32 = 524288 B  (unscaled per-tag sums)
//   cnt     : 128 i32      = 512 B
//   lastTag : 32768 i32    = 131072 B

// ---------------------------------------------------------------------------
// Kernel 1: lastTag[n] = max{ j : t2t[j][n] > 0 } (or -1), fused with zeroing
// P and cnt (plain stores; atomics to these happen only in later kernels).
// Math fact: deduce_direct_string's temp[i][n] is 1 iff i is the LAST covering
// tag of n (for ANY 0/1 coverage), so normalized t2t is one-hot / cnt[tag].
// ---------------------------------------------------------------------------
__global__ __launch_bounds__(256) void k_lasttag(const float* __restrict__ t2t,
                                                 int* __restrict__ lastTag,
                                                 float* __restrict__ P,
                                                 int* __restrict__ cnt) {
    __shared__ int part[8][32][4];
    const int tid = threadIdx.x;

    const int gid = blockIdx.x * 256 + tid;
    reinterpret_cast<float2*>(P)[gid] = make_float2(0.f, 0.f);
    if (gid < NTAG) cnt[gid] = 0;

    const int g = tid & 31;  // token group (4 tokens)
    const int c = tid >> 5;  // row chunk (16 rows)
    const int n0 = blockIdx.x * 128 + g * 4;
    const int j0 = c * 16;
    int l0 = -1, l1 = -1, l2 = -1, l3 = -1;
#pragma unroll
    for (int jj = 0; jj < 16; ++jj) {
        const int j = j0 + jj;
        const float4 v = *reinterpret_cast<const float4*>(t2t + (size_t)j * NTOK + n0);
        if (v.x > 0.f) l0 = j;
        if (v.y > 0.f) l1 = j;
        if (v.z > 0.f) l2 = j;
        if (v.w > 0.f) l3 = j;
    }
    part[c][g][0] = l0;
    part[c][g][1] = l1;
    part[c][g][2] = l2;
    part[c][g][3] = l3;
    __syncthreads();

    if (tid < 128) {
        int m = -1;
#pragma unroll
        for (int cc = 0; cc < 8; ++cc) m = max(m, part[cc][tid >> 2][tid & 3]);
        lastTag[blockIdx.x * 128 + tid] = m;
    }
}

// ---------------------------------------------------------------------------
// Kernel 2: segmented sum, software-pipelined (unchanged from round 3).
// ---------------------------------------------------------------------------
__global__ __launch_bounds__(256) void k_segsum(const float* __restrict__ inp,
                                                const int* __restrict__ lastTag,
                                                float* __restrict__ P,
                                                int* __restrict__ cnt) {
    __shared__ int tags[TOKS_PER_BLK];
    const int tid = threadIdx.x;
    const int n0 = blockIdx.x * TOKS_PER_BLK;
    if (tid < TOKS_PER_BLK) tags[tid] = lastTag[n0 + tid];
    __syncthreads();

    const int col = tid * 4;
    const float4* src = reinterpret_cast<const float4*>(inp) + (size_t)n0 * 256 + tid;

    float4 va[8], vb[8];
#pragma unroll
    for (int k = 0; k < 8; ++k) va[k] = src[(size_t)k * 256];

    float4 acc = make_float4(0.f, 0.f, 0.f, 0.f);
    int cur = tags[0];
    int runlen = 0;

#pragma unroll
    for (int gr = 0; gr < 4; ++gr) {
        if (gr < 3) {
#pragma unroll
            for (int k = 0; k < 8; ++k)
                vb[k] = src[(size_t)(gr + 1) * 8 * 256 + (size_t)k * 256];
        }
#pragma unroll
        for (int k = 0; k < 8; ++k) {
            const int tg = tags[gr * 8 + k];
            if (tg != cur) {  // wave-uniform (tags uniform across lanes)
                if (cur >= 0) {
                    float* p = P + (size_t)cur * DDIM + col;
                    atomicAdd(p + 0, acc.x);
                    atomicAdd(p + 1, acc.y);
                    atomicAdd(p + 2, acc.z);
                    atomicAdd(p + 3, acc.w);
                    if (tid == 0) atomicAdd(&cnt[cur], runlen);
                }
                acc = make_float4(0.f, 0.f, 0.f, 0.f);
                cur = tg;
                runlen = 0;
            }
            if (tg >= 0) {
                acc.x += va[k].x;
                acc.y += va[k].y;
                acc.z += va[k].z;
                acc.w += va[k].w;
                ++runlen;
            }
        }
#pragma unroll
        for (int k = 0; k < 8; ++k) va[k] = vb[k];
    }
    if (cur >= 0) {
        float* p = P + (size_t)cur * DDIM + col;
        atomicAdd(p + 0, acc.x);
        atomicAdd(p + 1, acc.y);
        atomicAdd(p + 2, acc.z);
        atomicAdd(p + 3, acc.w);
        if (tid == 0) atomicAdd(&cnt[cur], runlen);
    }
}

// ---------------------------------------------------------------------------
// Kernel 3: triangular recurrence, one WAVE per column (1024 waves -> every
// SIMD on the chip, vs 16 waves before). deduce_child(gm) == gm (inner loop
// provably a no-op). Lane l holds o[l] and o[64+l] in VGPRs; per-lane
// bit-transposed masks in 8 VGPRs; per-row masked sum via VALU DPP butterfly
// (xor1, xor2, pair{0-3}<->{4-7}, pair{0-7}<->{8-15}) + ds_swizzle xor16 +
// two readlanes -> wave-uniform total. ~120cy chain per row vs ~950 dependent
// 120cy LDS reads per column before. No LDS, no syncthreads.
// ---------------------------------------------------------------------------
template <int CTRL>
__device__ __forceinline__ float dpp_add(float x) {
    const int y = __builtin_amdgcn_update_dpp(0, __float_as_int(x), CTRL, 0xF, 0xF, true);
    return x + __int_as_float(y);
}

__global__ __launch_bounds__(256) void k_recur(const float* __restrict__ P,
                                               const int* __restrict__ gm,
                                               const int* __restrict__ cnt,
                                               float* __restrict__ out) {
    const int lane = threadIdx.x & 63;
    const int col = blockIdx.x * 4 + (threadIdx.x >> 6);  // one column per wave

    // Per-lane bit-transposed masks: bit r of wlo[r>>5] = (gm[r][lane] != 0).
    // Fully unrolled -> static indices -> stays in VGPRs (rule: runtime-indexed
    // arrays go to scratch).
    unsigned wlo[4] = {0u, 0u, 0u, 0u}, whi[4] = {0u, 0u, 0u, 0u};
#pragma unroll
    for (int r = 0; r < NTAG; ++r) {
        const int a = gm[r * NTAG + lane];
        const int b = gm[r * NTAG + 64 + lane];
        wlo[r >> 5] |= (unsigned)(a != 0) << (r & 31);
        whi[r >> 5] |= (unsigned)(b != 0) << (r & 31);
    }

    // o in registers, 1/cnt fused into the load.
    float o_lo = P[(size_t)lane * DDIM + col] * (1.0f / (float)cnt[lane]);
    float o_hi = P[(size_t)(64 + lane) * DDIM + col] * (1.0f / (float)cnt[64 + lane]);

#pragma unroll
    for (int i = NTAG - 1; i >= 0; --i) {
        const unsigned bl = (wlo[i >> 5] >> (i & 31)) & 1u;
        const unsigned bh = (whi[i >> 5] >> (i & 31)) & 1u;
        float s = (bl ? o_lo : 0.f) + (bh ? o_hi : 0.f);
        s = dpp_add<0xB1>(s);   // quad_perm(1,0,3,2): xor1
        s = dpp_add<0x4E>(s);   // quad_perm(2,3,0,1): xor2
        s = dpp_add<0x141>(s);  // row_half_mirror: pairs {0-3}<->{4-7}
        s = dpp_add<0x140>(s);  // row_mirror: pairs {0-7}<->{8-15}
        s += __int_as_float(__builtin_amdgcn_ds_swizzle(__float_as_int(s), 0x401F));  // xor16
        const float h0 = __int_as_float(__builtin_amdgcn_readlane(__float_as_int(s), 0));
        const float h1 = __int_as_float(__builtin_amdgcn_readlane(__float_as_int(s), 32));
        const float r = h0 + h1;  // wave-uniform total
        if (i >= 64) {
            if (lane == (i - 64)) o_hi = r;
        } else {
            if (lane == i) o_lo = r;
        }
    }

    out[(size_t)lane * DDIM + col] = o_lo;
    out[(size_t)(64 + lane) * DDIM + col] = o_hi;
}

// ---------------------------------------------------------------------------
extern "C" void kernel_launch(void* const* d_in, const int* in_sizes, int n_in,
                              void* d_out, int out_size, void* d_ws, size_t ws_size,
                              hipStream_t stream) {
    const float* inp = (const float*)d_in[0];  // (N, D)
    const float* t2t = (const float*)d_in[1];  // (T, N)
    const int* gm = (const int*)d_in[2];       // (T, T)
    float* out = (float*)d_out;                // (T, D)

    char* ws = (char*)d_ws;
    float* P = (float*)ws;                     // 524288 B
    int* cnt = (int*)(ws + 524288);            // 512 B
    int* lastTag = (int*)(ws + 524288 + 512);  // 131072 B

    k_lasttag<<<NTOK / 128, 256, 0, stream>>>(t2t, lastTag, P, cnt);
    k_segsum<<<NTOK / TOKS_PER_BLK, 256, 0, stream>>>(inp, lastTag, P, cnt);
    k_recur<<<DDIM / 4, 256, 0, stream>>>(P, gm, cnt, out);
}